// Round 9
// baseline (254.351 us; speedup 1.0000x reference)
//
#include <hip/hip_runtime.h>

// Izhikevich spiking neuron scan — few-cursor / long-run decomposition.
//
// x: [T=512, N=65536] f32. out: [T, N] f32 spike train (0.0 / 1.0).
//
// Round-9 theory: R8 showed (a) dense grid-window reads run at ~7 TB/s
// (prewarm: 128 MB in ~18 us) while the scan's reads cap at ~2.2 TB/s even
// when L3-RESIDENT — so the cap is the request-stream structure, not DRAM;
// (b) prewarm's per-block pieces are 4 KB too — it is fast because
// neighboring blocks read ADJACENT pieces (dense instantaneous window).
// The scan's same-chunk blocks start adjacent but drift in t, leaving each
// row covered by a sparse shifting subset of ~2048 cursors. Untested
// lever: cursor count x run length. This version: 256 blocks x 512 thr,
// 8 neurons/thread (2 float4 groups) -> each block reads a 16 KB
// CONTIGUOUS run per timestep (256 cursors, 8x fewer, 8x longer than any
// prior variant), exactly 1 block/CU. Writes stay inline (R2's 74 us
// single kernel beat R6's 93 us split; writes ride along free).
//
// Recurrence (bit-identical to all verified prior versions, absmax 0.0):
//   v = (4v^2 + 5v + 1.4 - r + x_t) * DT   (DT = 1/512)
//   r = 0.02 * (0.2v - v) * DT             (uses NEW v)
//   fire = v >= 0.3 ; fire -> v = -0.065, r += 0.008 ; out_t = fire
//
// Time-split justification (verified absmax=0 seven times): the map
// contracts prior state by ~(5/512)/step; 8 warmup steps shrink any
// init-state error below fp32 ulp.

#define T_STEPS 512
#define N_NEUR  65536
#define N4      (N_NEUR / 4)     // 16384 float4 columns
#define DT      (1.0f / 512.0f)
#define NCHUNK  16
#define TCH     (T_STEPS / NCHUNK)   // 32 timesteps per chunk
#define WARM    8
#define NP      4                // timestep rows per load batch
#define NBATCH  (TCH / NP)       // 8 batches per chunk
#define NSLAB   16               // 16 KB column slabs per 256 KB row

typedef float v4f __attribute__((ext_vector_type(4)));

__device__ __forceinline__ float izi_step(float xt, float& v, float& r) {
    v = (4.0f * v * v + 5.0f * v + 1.4f - r + xt) * DT;
    r = 0.02f * (0.2f * v - v) * DT;
    const bool fire = v >= 0.3f;
    if (fire) { v = -0.065f; r += 0.008f; }
    return fire ? 1.0f : 0.0f;
}

__device__ __forceinline__ v4f izi_step4(const v4f xt, v4f& v, v4f& r) {
    v4f o;
    float a, b;
    a = v.x; b = r.x; o.x = izi_step(xt.x, a, b); v.x = a; r.x = b;
    a = v.y; b = r.y; o.y = izi_step(xt.y, a, b); v.y = a; r.y = b;
    a = v.z; b = r.z; o.z = izi_step(xt.z, a, b); v.z = a; r.z = b;
    a = v.w; b = r.w; o.w = izi_step(xt.w, a, b); v.w = a; r.w = b;
    return o;
}

__global__ __launch_bounds__(512, 2) void izi_kernel(const v4f* __restrict__ x,
                                                     v4f* __restrict__ out) {
    const int tid = threadIdx.x;          // 0..511
    const int slab = blockIdx.x;          // 0..15: 16 KB column slab
    const int c = blockIdx.y;             // 0..15: time chunk
    const int tstart = c * TCH;

    // Thread owns float4 columns col0 and col1 (8 neurons). Block covers
    // f4 cols [slab*1024, slab*1024+1024) = one contiguous 16 KB run/row.
    const int col0 = slab * 1024 + tid;
    const int col1 = col0 + 512;

    v4f v0, r0, v1, r1;
    v0.x = v0.y = v0.z = v0.w = -0.065f;  v1 = v0;
    r0.x = r0.y = r0.z = r0.w = 0.0f;     r1 = r0;

    if (c > 0) {
        #pragma unroll
        for (int t = tstart - WARM; t < tstart; ++t) {
            const v4f a = x[(size_t)t * N4 + col0];
            const v4f b = x[(size_t)t * N4 + col1];
            (void)izi_step4(a, v0, r0);
            (void)izi_step4(b, v1, r1);
        }
    }

    // Ping-pong batches of NP rows x 2 groups; fully unrolled (static
    // indices -> registers, not scratch).
    v4f buf[2][NP][2];
    #pragma unroll
    for (int i = 0; i < NP; ++i) {
        buf[0][i][0] = x[(size_t)(tstart + i) * N4 + col0];
        buf[0][i][1] = x[(size_t)(tstart + i) * N4 + col1];
    }

    #pragma unroll
    for (int tb = 0; tb < NBATCH; ++tb) {
        const int cur = tb & 1;
        const int nxt = cur ^ 1;
        const int t0 = tstart + tb * NP;

        if (tb < NBATCH - 1) {
            // Batch-issue the next 4 rows' 8 loads before consuming these.
            #pragma unroll
            for (int i = 0; i < NP; ++i) {
                buf[nxt][i][0] = x[(size_t)(t0 + NP + i) * N4 + col0];
                buf[nxt][i][1] = x[(size_t)(t0 + NP + i) * N4 + col1];
            }
        }
        // Pin: loads above stay above the compute below.
        __builtin_amdgcn_sched_barrier(0);

        #pragma unroll
        for (int i = 0; i < NP; ++i) {
            const int t = t0 + i;
            const v4f o0 = izi_step4(buf[cur][i][0], v0, r0);
            __builtin_nontemporal_store(o0, &out[(size_t)t * N4 + col0]);
            const v4f o1 = izi_step4(buf[cur][i][1], v1, r1);
            __builtin_nontemporal_store(o1, &out[(size_t)t * N4 + col1]);
        }
    }
}

extern "C" void kernel_launch(void* const* d_in, const int* in_sizes, int n_in,
                              void* d_out, int out_size, void* d_ws, size_t ws_size,
                              hipStream_t stream) {
    const v4f* x = (const v4f*)d_in[0];
    v4f* out = (v4f*)d_out;
    // grid: 16 slabs x 16 chunks = 256 blocks of 512 threads — exactly
    // 1 block/CU (8 waves/CU); 256 read cursors with 16 KB runs per row.
    izi_kernel<<<dim3(NSLAB, NCHUNK), dim3(512), 0, stream>>>(x, out);
}

// Round 10
// 230.973 us; speedup vs baseline: 1.1012x; 1.1012x over previous
//
#include <hip/hip_runtime.h>

// Izhikevich spiking neuron scan — phase-pure bursts: load-all / compute-all /
// store-all per chunk, mirroring the instruction stream of the 7 TB/s
// prewarm sweep measured in round 8.
//
// x: [T=512, N=65536] f32. out: [T, N] f32 spike train (0.0 / 1.0).
//
// Round-10 theory: R8's prewarm moved the same 128 MB (strided per-wave
// jumps, 2048 blocks) at ~7 TB/s; every scan variant caps at 2.2-2.9 TB/s.
// All prior candidate mechanisms are individually nulled (in-flight depth
// R5, R/W mix R6, L3 residency R8, cursor geometry R9). The last untested
// difference is PHASE PURITY: prewarm issues 16 independent loads
// back-to-back with no consumer/store/sched_barrier between them; all scan
// variants chop each wave's memory stream into 4-8-row bursts separated by
// dependent-chain compute and store epochs. This version: per thread,
// burst ALL 32 chunk loads into buf[32] (64 VGPR, static indices, 16 KB
// in flight per wave — numerically identical to prewarm), then run the
// 32-step recurrence purely from registers overwriting buf[i] in place,
// then burst 32 NT stores. Waves in different phases overlap in the CU.
//
// Recurrence (bit-identical to all verified prior versions, absmax 0.0):
//   v = (4v^2 + 5v + 1.4 - r + x_t) * DT   (DT = 1/512)
//   r = 0.02 * (0.2v - v) * DT             (uses NEW v)
//   fire = v >= 0.3 ; fire -> v = -0.065, r += 0.008 ; out_t = fire
//
// Time-split justification (verified absmax=0 eight times): the map
// contracts prior state by ~(5/512)/step; 8 warmup steps shrink any
// init-state error below fp32 ulp. TCH=32 / WARM=8 matches R2's verified
// numerical path exactly.

#define T_STEPS 512
#define N_NEUR  65536
#define N2      (N_NEUR / 2)     // 32768 float2 columns
#define DT      (1.0f / 512.0f)
#define NCHUNK  16
#define TCH     (T_STEPS / NCHUNK)   // 32 timesteps per chunk
#define WARM    8

typedef float v2f __attribute__((ext_vector_type(2)));

__device__ __forceinline__ float izi_step(float xt, float& v, float& r) {
    v = (4.0f * v * v + 5.0f * v + 1.4f - r + xt) * DT;
    r = 0.02f * (0.2f * v - v) * DT;
    const bool fire = v >= 0.3f;
    if (fire) { v = -0.065f; r += 0.008f; }
    return fire ? 1.0f : 0.0f;
}

__device__ __forceinline__ v2f izi_step2(const v2f xt, v2f& v, v2f& r) {
    v2f o;
    float vx = v.x, rx = r.x, vy = v.y, ry = r.y;
    o.x = izi_step(xt.x, vx, rx);
    o.y = izi_step(xt.y, vy, ry);
    v.x = vx; r.x = rx; v.y = vy; r.y = ry;
    return o;
}

__global__ __launch_bounds__(256, 4) void izi_kernel(const v2f* __restrict__ x,
                                                     v2f* __restrict__ out) {
    const int col = blockIdx.x * 256 + threadIdx.x;  // float2 column, coalesced
    const int c = blockIdx.y;                        // time chunk 0..15
    const int tstart = c * TCH;

    v2f v; v.x = -0.065f; v.y = -0.065f;
    v2f r; r.x = 0.0f;    r.y = 0.0f;

    if (c > 0) {
        // Warmup, same phase-pure shape: burst 8 loads, then consume.
        v2f wbuf[WARM];
        #pragma unroll
        for (int i = 0; i < WARM; ++i)
            wbuf[i] = x[(size_t)(tstart - WARM + i) * N2 + col];
        __builtin_amdgcn_sched_barrier(0);
        #pragma unroll
        for (int i = 0; i < WARM; ++i)
            (void)izi_step2(wbuf[i], v, r);
    }

    // Phase 1: burst ALL 32 loads back-to-back (no consumer in between) —
    // 16 KB in flight per wave, the prewarm instruction stream.
    v2f buf[TCH];
    #pragma unroll
    for (int i = 0; i < TCH; ++i)
        buf[i] = x[(size_t)(tstart + i) * N2 + col];
    __builtin_amdgcn_sched_barrier(0);

    // Phase 2: 32-step recurrence purely in registers; output overwrites
    // buf[i] in place (static indices -> registers, zero extra VGPR).
    #pragma unroll
    for (int i = 0; i < TCH; ++i)
        buf[i] = izi_step2(buf[i], v, r);
    __builtin_amdgcn_sched_barrier(0);

    // Phase 3: burst 32 non-temporal stores (output never re-read).
    #pragma unroll
    for (int i = 0; i < TCH; ++i)
        __builtin_nontemporal_store(buf[i], &out[(size_t)(tstart + i) * N2 + col]);
}

extern "C" void kernel_launch(void* const* d_in, const int* in_sizes, int n_in,
                              void* d_out, int out_size, void* d_ws, size_t ws_size,
                              hipStream_t stream) {
    const v2f* x = (const v2f*)d_in[0];
    v2f* out = (v2f*)d_out;
    // grid: 128 neuron-blocks x 16 time-chunks = 2048 blocks of 256 thr.
    // VGPR ~90 -> 4 waves/EU (16 waves/CU); occupancy is a second-order
    // effect here (R0 vs R9: 32 vs 8 waves/CU = 82 vs 100 us).
    izi_kernel<<<dim3(N2 / 256, NCHUNK), dim3(256), 0, stream>>>(x, out);
}

// Round 11
// 228.248 us; speedup vs baseline: 1.1144x; 1.0119x over previous
//
#include <hip/hip_runtime.h>

// Izhikevich spiking neuron scan — FINAL: revert to the round-2 kernel, the
// best harness-verified variant (bench 224.3 us, ~74.7 us/dispatch).
//
// x: [T=512, N=65536] f32. out: [T, N] f32 spike train (0.0 / 1.0).
//
// Recurrence per neuron (bit-identical across all 9 verified variants):
//   v = (4v^2 + 5v + 1.4 - r + x_t) * DT   (DT = 1/512)
//   r = 0.02 * (0.2v - v) * DT             (uses NEW v)
//   fire = v >= 0.3 ; fire -> v = -0.065, r += 0.008 ; out_t = fire
//
// Time-split justification (verified absmax=0 nine times): the map
// contracts prior state by ~(5/512)/step; 8 warmup steps shrink any
// init-state error below fp32 ulp.
//
// WHY THIS IS THE CEILING (session falsification ledger, R0-R10):
//   The kernel is bound by the READ throughput of its access pattern:
//   ~2048 cursors each reading 2-4 KB islands strided 256 KB sustain only
//   ~2.5-2.9 TB/s on this fabric, independent of:
//     - guaranteed in-flight bytes: 8 -> 96 KB/CU via counted-vmcnt
//       global_load_lds DMA (R5: no change)
//     - R/W stream mixing: pure-read bitpack split (R6: read side still
//       capped; scattered NT WRITES run ~5+ TB/s)
//     - DRAM row locality / L3 residency: a 7 TB/s contiguous prewarm
//       making x fully Infinity-Cache-resident did not speed the scan at
//       all (R8) — the cap is upstream of DRAM
//     - cursor count x run length: 256 cursors x 16 KB runs (R9: slower)
//     - load width (4/8/16 B), occupancy (8-32 waves/CU), reg vs DMA
//       staging, phase-pure load bursts (R5/R10)
//   Floor arithmetic: 158 MB logical reads / 2.6 TB/s ~= 61 us + ~14 us
//   un-overlapped write residue = ~75 us = this kernel's measured 74.7 us.
//   The 6.3 TB/s copy roofline (41 us) requires a dense sweeping request
//   window that a [T][N]-strided stateful scan cannot emit; re-layout
//   passes (transpose/gather) inherit the scattered side at the same cap
//   and measure net-slower (R6: 93 us).

#define T_STEPS 512
#define N_NEUR  65536
#define N2      (N_NEUR / 2)     // 32768 float2 columns
#define DT      (1.0f / 512.0f)
#define TCH     32               // timesteps per chunk (512/16)
#define WARM    8                // warmup steps to converge state at chunk start
#define NP      8                // prefetch batch depth (timesteps per tile)
#define NBLK    (TCH / NP)       // 4 tiles per chunk

typedef float v2f __attribute__((ext_vector_type(2)));

__device__ __forceinline__ float izi_step(float xt, float& v, float& r) {
    v = (4.0f * v * v + 5.0f * v + 1.4f - r + xt) * DT;
    r = 0.02f * (0.2f * v - v) * DT;
    const bool fire = v >= 0.3f;
    if (fire) { v = -0.065f; r += 0.008f; }
    return fire ? 1.0f : 0.0f;
}

__device__ __forceinline__ v2f izi_step2(const v2f xt, v2f& v, v2f& r) {
    v2f o;
    float vx = v.x, rx = r.x, vy = v.y, ry = r.y;
    o.x = izi_step(xt.x, vx, rx);
    o.y = izi_step(xt.y, vy, ry);
    v.x = vx; r.x = rx; v.y = vy; r.y = ry;
    return o;
}

__global__ __launch_bounds__(256, 4) void izi_kernel(const v2f* __restrict__ x,
                                                     v2f* __restrict__ out) {
    const int col = blockIdx.x * 256 + threadIdx.x;  // float2 column, coalesced
    const int c = blockIdx.y;                        // time chunk 0..15
    const int tstart = c * TCH;

    v2f v; v.x = -0.065f; v.y = -0.065f;
    v2f r; r.x = 0.0f;    r.y = 0.0f;

    if (c > 0) {
        // Warmup: addresses state-independent; full unroll batches the loads.
        #pragma unroll
        for (int t = tstart - WARM; t < tstart; ++t) {
            const v2f xt = x[(size_t)t * N2 + col];
            (void)izi_step2(xt, v, r);
        }
    }

    // Ping-pong pipeline: buf[2][NP], fully unrolled so every index is
    // compile-time constant (registers, not scratch).
    v2f buf[2][NP];
    #pragma unroll
    for (int i = 0; i < NP; ++i)
        buf[0][i] = x[(size_t)(tstart + i) * N2 + col];

    #pragma unroll
    for (int tb = 0; tb < NBLK; ++tb) {
        const int cur = tb & 1;
        const int nxt = cur ^ 1;
        const int t0 = tstart + tb * NP;

        if (tb < NBLK - 1) {
            // Batch-issue next tile's 8 loads before touching this tile.
            #pragma unroll
            for (int i = 0; i < NP; ++i)
                buf[nxt][i] = x[(size_t)(t0 + NP + i) * N2 + col];
        }
        // Pin: loads above stay above the compute below.
        __builtin_amdgcn_sched_barrier(0);

        #pragma unroll
        for (int i = 0; i < NP; ++i) {
            const v2f o = izi_step2(buf[cur][i], v, r);
            __builtin_nontemporal_store(o, &out[(size_t)(t0 + i) * N2 + col]);
        }
    }
}

extern "C" void kernel_launch(void* const* d_in, const int* in_sizes, int n_in,
                              void* d_out, int out_size, void* d_ws, size_t ws_size,
                              hipStream_t stream) {
    const v2f* x = (const v2f*)d_in[0];
    v2f* out = (v2f*)d_out;
    // grid: 128 neuron-blocks x 16 time-chunks = 2048 blocks (8 per CU,
    // 32 waves/CU — full wave-slot occupancy at VGPR<=64).
    izi_kernel<<<dim3(N2 / 256, T_STEPS / TCH), dim3(256), 0, stream>>>(x, out);
}